// Round 2
// baseline (152.339 us; speedup 1.0000x reference)
//
#include <hip/hip_runtime.h>

#define B_ 8
#define T_ 2048
#define H_ 256
#define PSTR 40                  // P LDS row stride (elems)
#define SCALE2 0.0901684403f     // (1/16) * log2(e)
#define SLOPE2 0.00563552752f    // 2^-8 * log2(e)
#define ELEMS ((size_t)B_ * T_ * H_)

typedef __attribute__((ext_vector_type(8))) short bf16x8;
typedef __attribute__((ext_vector_type(4))) float f32x4;

#define MFMA16(a, b, c) __builtin_amdgcn_mfma_f32_16x16x32_bf16((a), (b), (c), 0, 0, 0)

__device__ __forceinline__ ushort f2bf(float f) {
  unsigned u = __float_as_uint(f);
  u += 0x7FFFu + ((u >> 16) & 1u);   // RNE; finite inputs
  return (ushort)(u >> 16);
}

// async 16B/lane global->LDS DMA (contiguous: LDS = uniform base + lane*16)
__device__ __forceinline__ void gl_lds16(const ushort* g, ushort* l) {
  __builtin_amdgcn_global_load_lds(
      (const __attribute__((address_space(1))) unsigned int*)g,
      (__attribute__((address_space(3))) unsigned int*)l, 16, 0, 0);
}

// ---- prologue: blocks [0,1024) RoPE(k)->bf16 blocked ktile; [1024,2048) v transpose ----
// ktile layout: [b][it=t/32][d8=d/8][kv=t%32][8]   (16KB contiguous per (b,it) tile)
// vtile layout: [b][it][q4=(t%32)/8][h][8]
__global__ void prep_kernel(const float* __restrict__ k, const float* __restrict__ v,
                            ushort* __restrict__ kt, ushort* __restrict__ vt) {
  __shared__ ushort tile[64][72];
  const int bid = blockIdx.x;
  const int tid = threadIdx.x;
  if (bid < 1024) {
    // K RoPE: thread = (bt, d8); reads 2x32B coalesced, writes 2x16B vector stores
    int idx = bid * 256 + tid;          // over B*T*16
    int d8 = idx & 15;
    int bt = idx >> 4;
    int t = bt & (T_ - 1);
    int b = bt >> 11;
    size_t base = (size_t)bt * H_ + d8 * 8;
    float4 a0 = *(const float4*)(k + base);
    float4 a1 = *(const float4*)(k + base + 4);
    float4 c0 = *(const float4*)(k + base + 128);
    float4 c1 = *(const float4*)(k + base + 132);
    float av[8] = {a0.x, a0.y, a0.z, a0.w, a1.x, a1.y, a1.z, a1.w};
    float cv[8] = {c0.x, c0.y, c0.z, c0.w, c1.x, c1.y, c1.z, c1.w};
    bf16x8 lo, hi;
#pragma unroll
    for (int e = 0; e < 8; ++e) {
      int j = d8 * 8 + e;
      float rv = (float)t * exp2f((float)j * -0.103810252959f) * 0.15915494309f;
      float fr = rv - floorf(rv);
      float sn = __builtin_amdgcn_sinf(fr), cs = __builtin_amdgcn_cosf(fr);
      lo[e] = (short)f2bf(av[e] * cs - cv[e] * sn);
      hi[e] = (short)f2bf(cv[e] * cs + av[e] * sn);
    }
    size_t kdst = (((size_t)(b * 64 + (t >> 5)) * 32 + d8) * 32 + (t & 31)) * 8;
    *(bf16x8*)(kt + kdst) = lo;
    *(bf16x8*)(kt + kdst + 4096) = hi;   // d8 + 16
  } else {
    // V transpose into blocked vtile, 64x64 tiles, XOR-8 swizzle in LDS
    int bid2 = bid - 1024;
    int b = bid2 >> 7, rem = bid2 & 127;
    int h0 = (rem >> 5) * 64, t0 = (rem & 31) * 64;
    int c4 = tid & 15, r0 = tid >> 4;
#pragma unroll
    for (int p = 0; p < 4; ++p) {
      int row = r0 + p * 16;
      const float4 f = *(const float4*)(v + ((size_t)(b * T_ + t0 + row)) * H_ + h0 + c4 * 4);
      ushort4 u;
      u.x = f2bf(f.x); u.y = f2bf(f.y); u.z = f2bf(f.z); u.w = f2bf(f.w);
      *(ushort4*)&tile[row][(c4 * 4) ^ (8 * ((row >> 3) & 7))] = u;
    }
    __syncthreads();
#pragma unroll
    for (int p = 0; p < 2; ++p) {
      int c = tid + p * 256;
      int h = c >> 3, tc = (c & 7) * 8;
      int xo = 8 * (c & 7);
      ushort4 u0, u1;
      u0.x = tile[tc + 0][h ^ xo]; u0.y = tile[tc + 1][h ^ xo];
      u0.z = tile[tc + 2][h ^ xo]; u0.w = tile[tc + 3][h ^ xo];
      u1.x = tile[tc + 4][h ^ xo]; u1.y = tile[tc + 5][h ^ xo];
      u1.z = tile[tc + 6][h ^ xo]; u1.w = tile[tc + 7][h ^ xo];
      int tg = t0 + tc;
      size_t dst = (((size_t)(b * 64 + (tg >> 5)) * 4 + ((tg >> 3) & 3)) * 256 + (h0 + h)) * 8;
      *(ushort4*)(vt + dst) = u0;
      *(ushort4*)(vt + dst + 4) = u1;
    }
  }
}

// ---- Flash attention: 256-thr blocks, 4 waves x 32 q-rows (mt=2), q-tile 128.
// kv-split S = gridDim.z (4 preferred, 2 fallback): S=4 -> 512 blocks = 2/CU
// = 2 waves/SIMD with register-reused fragments (66 MFMA : 34 ds_read per iter).
// K+V double-buffered gl_lds DMA, counted vmcnt(8) acquire, lgkm-only release.
__global__ __launch_bounds__(256, 2)
void attn_kernel(const float* __restrict__ q, const ushort* __restrict__ kt,
                 const ushort* __restrict__ vt, float* __restrict__ out,
                 float* __restrict__ opart, float* __restrict__ lpart) {
  __shared__ ushort Ksh[2][8192];       // [buf][d8][kv32][8]  32 KB
  __shared__ ushort Vsh[2][8192];       // [buf][q4][h256][8]  32 KB
  __shared__ ushort Psh[4][32 * PSTR];  // per-wave P          10 KB

  const int tid = threadIdx.x;
  const int w = tid >> 6, lane = tid & 63, quad = lane >> 4, l16 = lane & 15;
  const int b = blockIdx.x;             // linear%8==b -> XCD affinity
  const int q0 = blockIdx.y * 128;
  const int sp = blockIdx.z;
  const int S = gridDim.z;
  const int niter = (T_ / 32) / S;
  const int kvb = sp * (T_ / S);

  // ---- in-register RoPE of this wave's 32 Q rows into A-frags ----
  bf16x8 aq[2][8];
  {
    const float* qb = q + ((size_t)(b * T_) + q0 + w * 32) * H_;
#pragma unroll
    for (int mt = 0; mt < 2; ++mt) {
      int t = q0 + w * 32 + mt * 16 + l16;
      float qv[8][8];
#pragma unroll
      for (int ks = 0; ks < 8; ++ks) {
        float4 x0 = *(const float4*)(qb + (size_t)(mt * 16 + l16) * H_ + ks * 32 + quad * 8);
        float4 x1 = *(const float4*)(qb + (size_t)(mt * 16 + l16) * H_ + ks * 32 + quad * 8 + 4);
        qv[ks][0] = x0.x; qv[ks][1] = x0.y; qv[ks][2] = x0.z; qv[ks][3] = x0.w;
        qv[ks][4] = x1.x; qv[ks][5] = x1.y; qv[ks][6] = x1.z; qv[ks][7] = x1.w;
      }
#pragma unroll
      for (int ks = 0; ks < 4; ++ks)
#pragma unroll
        for (int e = 0; e < 8; ++e) {
          int d = ks * 32 + quad * 8 + e;
          float rv = (float)t * exp2f((float)d * -0.103810252959f) * 0.15915494309f;
          float fr = rv - floorf(rv);
          float sn = __builtin_amdgcn_sinf(fr), cs = __builtin_amdgcn_cosf(fr);
          aq[mt][ks][e]     = (short)f2bf(qv[ks][e] * cs - qv[ks + 4][e] * sn);
          aq[mt][ks + 4][e] = (short)f2bf(qv[ks + 4][e] * cs + qv[ks][e] * sn);
        }
    }
  }

  const f32x4 fzero = {0.f, 0.f, 0.f, 0.f};
  f32x4 O[2][16], lac[2];
#pragma unroll
  for (int mt = 0; mt < 2; ++mt) {
    lac[mt] = fzero;
#pragma unroll
    for (int ht = 0; ht < 16; ++ht) O[mt][ht] = fzero;
  }
  bf16x8 vones;
#pragma unroll
  for (int i = 0; i < 8; ++i) vones[i] = (short)0x3F80;

  const ushort* ktb = kt + (size_t)(b * 64 + sp * niter) * 8192;
  const ushort* vtb = vt + (size_t)(b * 64 + sp * niter) * 8192;
  const int stoff = tid * 8;            // elems: lane*16B over 256 threads (4KB/round)

  // preload tiles 0 and 1 (8 DMA instrs per thread per tile)
#pragma unroll
  for (int tt = 0; tt < 2; ++tt) {
    const ushort* kg = ktb + (size_t)tt * 8192;
    const ushort* vg = vtb + (size_t)tt * 8192;
#pragma unroll
    for (int i = 0; i < 4; ++i) {
      gl_lds16(kg + stoff + i * 2048, &Ksh[tt][stoff + i * 2048]);
      gl_lds16(vg + stoff + i * 2048, &Vsh[tt][stoff + i * 2048]);
    }
  }

  const float arb = SLOPE2 * (float)(q0 + w * 32 + quad * 4);

  for (int it = 0; it < niter; ++it) {
    const int p = it & 1;
    // acquire: tile(it)'s 8 DMAs landed (issued 2 iters ago); tile(it+1)'s 8 in flight
    __builtin_amdgcn_sched_barrier(0);
    if (it == niter - 1) __builtin_amdgcn_s_waitcnt(0x0070);   // vmcnt(0) lgkm(0)
    else                 __builtin_amdgcn_s_waitcnt(0x0F78);   // vmcnt(8)
    __builtin_amdgcn_s_barrier();
    __builtin_amdgcn_sched_barrier(0);

    // QK on Ksh[p]: each kf feeds 2 MFMAs (mt register reuse)
    f32x4 s[2][2] = {{fzero, fzero}, {fzero, fzero}};
    __builtin_amdgcn_s_setprio(1);
#pragma unroll
    for (int ks = 0; ks < 8; ++ks)
#pragma unroll
      for (int nt = 0; nt < 2; ++nt) {
        bf16x8 kf = *(const bf16x8*)&Ksh[p][((ks * 4 + quad) * 32 + nt * 16 + l16) * 8];
        s[0][nt] = MFMA16(aq[0][ks], kf, s[0][nt]);
        s[1][nt] = MFMA16(aq[1][ks], kf, s[1][nt]);
      }
    __builtin_amdgcn_s_setprio(0);

    // p = exp2(s*SCALE2 + SLOPE2*(col-row)) -> wave-private Psh
#pragma unroll
    for (int nt = 0; nt < 2; ++nt) {
      float ac = SLOPE2 * (float)(kvb + it * 32 + nt * 16 + l16);
#pragma unroll
      for (int mt = 0; mt < 2; ++mt)
#pragma unroll
        for (int r = 0; r < 4; ++r) {
          float a0 = ac - arb - SLOPE2 * (float)(mt * 16 + r);
          float pv = __builtin_amdgcn_exp2f(fmaf(s[mt][nt][r], SCALE2, a0));
          Psh[w][(mt * 16 + quad * 4 + r) * PSTR + nt * 16 + l16] = f2bf(pv);
        }
    }

    // PV + rowsum via ones-MFMA (lgkmcnt orders the wave-private write->read);
    // each vf feeds 2 MFMAs (mt register reuse)
    bf16x8 pf0 = *(const bf16x8*)&Psh[w][l16 * PSTR + quad * 8];
    bf16x8 pf1 = *(const bf16x8*)&Psh[w][(16 + l16) * PSTR + quad * 8];
    __builtin_amdgcn_s_setprio(1);
    lac[0] = MFMA16(pf0, vones, lac[0]);
    lac[1] = MFMA16(pf1, vones, lac[1]);
#pragma unroll
    for (int ht = 0; ht < 16; ++ht) {
      bf16x8 vf = *(const bf16x8*)&Vsh[p][(quad * 256 + ht * 16 + l16) * 8];
      O[0][ht] = MFMA16(pf0, vf, O[0][ht]);
      O[1][ht] = MFMA16(pf1, vf, O[1][ht]);
    }
    __builtin_amdgcn_s_setprio(0);

    // release: drain this wave's LDS reads, barrier -> buf[p] free for DMA
    __builtin_amdgcn_sched_barrier(0);
    __builtin_amdgcn_s_waitcnt(0xC07F);   // lgkmcnt(0) only
    __builtin_amdgcn_s_barrier();
    __builtin_amdgcn_sched_barrier(0);

    // prefetch tile(it+2) into the buffer just freed (same parity)
    if (it < niter - 2) {
      const ushort* kg = ktb + (size_t)(it + 2) * 8192;
      const ushort* vg = vtb + (size_t)(it + 2) * 8192;
#pragma unroll
      for (int i = 0; i < 4; ++i) {
        gl_lds16(kg + stoff + i * 2048, &Ksh[p][stoff + i * 2048]);
        gl_lds16(vg + stoff + i * 2048, &Vsh[p][stoff + i * 2048]);
      }
    }
  }

  // epilogue: unnormalized O-partial + l-partial
  float* od = (sp == 0) ? out : (opart + (size_t)(sp - 1) * ELEMS);
  float* ob = od + ((size_t)(b * T_) + q0 + w * 32) * H_;
#pragma unroll
  for (int mt = 0; mt < 2; ++mt)
#pragma unroll
    for (int r = 0; r < 4; ++r) {
      int row = mt * 16 + quad * 4 + r;
#pragma unroll
      for (int ht = 0; ht < 16; ++ht)
        ob[(size_t)row * H_ + ht * 16 + l16] = O[mt][ht][r];
    }
  if (l16 == 0) {
#pragma unroll
    for (int mt = 0; mt < 2; ++mt)
#pragma unroll
      for (int r = 0; r < 4; ++r)
        lpart[(size_t)(sp * B_ + b) * T_ + q0 + w * 32 + mt * 16 + quad * 4 + r] =
            lac[mt][r];
  }
}

// ---- combine: out = (O0 + ... + O_{S-1}) / (l0 + ... + l_{S-1}) ----
__global__ void combine_kernel(float* __restrict__ out, const float* __restrict__ opart,
                               const float* __restrict__ lpart, int S) {
  int idx = blockIdx.x * 256 + threadIdx.x;   // over B*T*H/4
  int row = idx >> 6;
  float l = lpart[row];
  for (int s = 1; s < S; ++s) l += lpart[(size_t)s * B_ * T_ + row];
  float inv = 1.0f / l;
  float4 a = ((const float4*)out)[idx];
  for (int s = 1; s < S; ++s) {
    float4 c = ((const float4*)opart)[(size_t)(s - 1) * (ELEMS / 4) + idx];
    a.x += c.x; a.y += c.y; a.z += c.z; a.w += c.w;
  }
  a.x *= inv; a.y *= inv; a.z *= inv; a.w *= inv;
  ((float4*)out)[idx] = a;
}

extern "C" void kernel_launch(void* const* d_in, const int* in_sizes, int n_in,
                              void* d_out, int out_size, void* d_ws, size_t ws_size,
                              hipStream_t stream) {
  const float* q = (const float*)d_in[0];
  const float* k = (const float*)d_in[1];
  const float* v = (const float*)d_in[2];
  float* out = (float*)d_out;

  ushort* kt = (ushort*)d_ws;
  ushort* vt = kt + ELEMS;
  float* opart = (float*)(vt + ELEMS);
  // S=4 needs: 2*ELEMS*2 (kt,vt) + 3*ELEMS*4 (oparts) + 4*B*T*4 (lpart)
  const size_t need4 = ELEMS * 4 + 3 * ELEMS * 4 + (size_t)4 * B_ * T_ * 4;
  const int S = (ws_size >= need4) ? 4 : 2;
  float* lpart = opart + (size_t)(S - 1) * ELEMS;

  prep_kernel<<<dim3(2048), 256, 0, stream>>>(k, v, kt, vt);
  attn_kernel<<<dim3(B_, T_ / 128, S), 256, 0, stream>>>(q, kt, vt, out, opart, lpart);
  combine_kernel<<<dim3((B_ * T_ * H_ / 4) / 256), 256, 0, stream>>>(out, opart, lpart, S);
}